// Round 1
// baseline (139.484 us; speedup 1.0000x reference)
//
#include <hip/hip_runtime.h>

// Batched Thomas solve, B=2048 rows, N=8192.
//   a_i = alpha_{i-1}^2 (a_0=0), b_i = 1+alpha_i^3, c_i = alpha_{i+1}^2+2*alpha_{i+1} (c_{N-1}=0)
// Forward:  denom = b - a*cp_prev; cp = c/denom; dp = (f - a*dp_prev)/denom
// Backward: u_i = dp_i - cp_i * u_{i+1},  u_N = 0
//
// Parallelization: one block per row; 256 threads x 32-element contiguous chunks.
// Forward recurrence in homogeneous coords (x,y,z), cp=x/z, dp=y/z is linear:
//   M_i = [[0,0,c],[0,-a,f],[-a,0,b]]; products closed under [[p,0,q],[r,s,t],[u,0,v]].
// Phase A: per-thread chunk map compose (regs). Phase B: LDS Hillis-Steele scan of maps.
// Phase C: replay chunk with true incoming (cp,dp), cp/dp kept in REGISTERS.
// Phase D: backward affine (A,B) per chunk + reversed scan, final back-substitution, float4 stores.

#define NN 8192
#define TB 256
#define CH 32   // NN / TB

__device__ __forceinline__ float frcp(float x) { return __builtin_amdgcn_rcpf(x); }

__global__ __launch_bounds__(TB, 2)
void thomas_scan_kernel(const float* __restrict__ alpha,
                        const float* __restrict__ fvec,
                        float* __restrict__ out)
{
    __shared__ float sm0[TB], sm1[TB], sm2[TB], sm3[TB], sm4[TB], sm5[TB], sm6[TB];
    __shared__ float sA[TB], sB[TB];

    const int t   = threadIdx.x;
    const int row = blockIdx.x;
    const float* __restrict__ arow = alpha + (size_t)row * NN;
    const int base = t * CH;

    // ---- load alpha chunk + halo, f chunk (all into registers) ----
    float va[CH], vf[CH];
    {
        const float4* a4 = reinterpret_cast<const float4*>(arow + base);
        const float4* f4 = reinterpret_cast<const float4*>(fvec + base);
        #pragma unroll
        for (int k = 0; k < CH / 4; ++k) {
            float4 x = a4[k];
            va[4*k+0] = x.x; va[4*k+1] = x.y; va[4*k+2] = x.z; va[4*k+3] = x.w;
            float4 y = f4[k];
            vf[4*k+0] = y.x; vf[4*k+1] = y.y; vf[4*k+2] = y.z; vf[4*k+3] = y.w;
        }
    }
    const float aL = (t > 0)      ? arow[base - 1]  : 0.0f;  // alpha_{base-1}; 0 => a_0 = 0
    const float aR = (t < TB - 1) ? arow[base + CH] : 0.0f;  // alpha_{base+CH}; 0 => c_{N-1} = 0

    // ---- Phase A: compose chunk map T <- M_i * T ----
    float p = 1.f, q = 0.f, r = 0.f, s = 1.f, tt = 0.f, u = 0.f, v = 1.f;
    #pragma unroll
    for (int k = 0; k < CH; ++k) {
        const float am1 = (k == 0)      ? aL : va[k-1];
        const float ap1 = (k == CH - 1) ? aR : va[k+1];
        const float ai = am1 * am1;
        const float bi = 1.0f + va[k] * va[k] * va[k];
        const float ci = ap1 * (ap1 + 2.0f);
        const float fi = vf[k];
        const float np = ci * u;
        const float nq = ci * v;
        const float nr = fi * u - ai * r;
        const float ns = -ai * s;
        const float nt = fi * v - ai * tt;
        const float nu = bi * u - ai * p;
        const float nv = bi * v - ai * q;
        p = np; q = nq; r = nr; s = ns; tt = nt; u = nu; v = nv;
    }
    {   // homogeneous map: normalize by v (keeps scan entries O(1))
        const float inv = frcp(v);
        p *= inv; q *= inv; r *= inv; s *= inv; tt *= inv; u *= inv; v = 1.0f;
    }
    sm0[t] = p; sm1[t] = q; sm2[t] = r; sm3[t] = s; sm4[t] = tt; sm5[t] = u; sm6[t] = v;
    __syncthreads();

    // ---- Phase B: inclusive scan of maps (new = mine o earlier) ----
    #pragma unroll
    for (int off = 1; off < TB; off <<= 1) {
        float p1=0, q1=0, r1=0, s1=0, t1=0, u1=0, v1=0;
        const bool act = (t >= off);
        if (act) {
            p1 = sm0[t-off]; q1 = sm1[t-off]; r1 = sm2[t-off]; s1 = sm3[t-off];
            t1 = sm4[t-off]; u1 = sm5[t-off]; v1 = sm6[t-off];
        }
        __syncthreads();
        if (act) {
            const float np = p*p1 + q*u1;
            const float nq = p*q1 + q*v1;
            const float nr = r*p1 + s*r1 + tt*u1;
            const float ns = s*s1;
            const float nt = r*q1 + s*t1 + tt*v1;
            const float nu = u*p1 + v*u1;
            const float nv = u*q1 + v*v1;
            const float inv = frcp(nv);
            p = np*inv; q = nq*inv; r = nr*inv; s = ns*inv; tt = nt*inv; u = nu*inv; v = 1.0f;
        }
        sm0[t] = p; sm1[t] = q; sm2[t] = r; sm3[t] = s; sm4[t] = tt; sm5[t] = u; sm6[t] = v;
        __syncthreads();
    }

    // incoming state = third column of prefix(t-1) applied to s0=(0,0,1)
    float cp, dp;
    if (t == 0) { cp = 0.0f; dp = 0.0f; }
    else {
        const float rz = frcp(sm6[t-1]);
        cp = sm1[t-1] * rz;
        dp = sm4[t-1] * rz;
    }

    // ---- Phase C: true forward sweep; cp/dp kept in registers ----
    float cpv[CH], dpv[CH];
    #pragma unroll
    for (int k = 0; k < CH; ++k) {
        const float am1 = (k == 0)      ? aL : va[k-1];
        const float ap1 = (k == CH - 1) ? aR : va[k+1];
        const float ai = am1 * am1;
        const float bi = 1.0f + va[k] * va[k] * va[k];
        const float ci = ap1 * (ap1 + 2.0f);
        const float fi = vf[k];
        const float rd = frcp(bi - ai * cp);
        cp = ci * rd;
        dp = (fi - ai * dp) * rd;
        cpv[k] = cp;
        dpv[k] = dp;
    }

    // ---- Phase D: backward. chunk map u_left = A*u_right + B ----
    float A = 1.0f, Bb = 0.0f;
    #pragma unroll
    for (int k = CH - 1; k >= 0; --k) {
        Bb = dpv[k] - cpv[k] * Bb;
        A  = -cpv[k] * A;
    }
    sA[t] = A; sB[t] = Bb;
    __syncthreads();
    #pragma unroll
    for (int off = 1; off < TB; off <<= 1) {
        float A1 = 0.f, B1 = 0.f;
        const bool act = (t + off < TB);
        if (act) { A1 = sA[t + off]; B1 = sB[t + off]; }
        __syncthreads();
        if (act) { Bb = A * B1 + Bb; A = A * A1; }
        sA[t] = A; sB[t] = Bb;
        __syncthreads();
    }
    const float u_in = (t == TB - 1) ? 0.0f : sB[t + 1];

    // ---- final back-substitution + coalesced-ish float4 stores ----
    float uv[CH];
    float un = u_in;
    #pragma unroll
    for (int k = CH - 1; k >= 0; --k) {
        un = dpv[k] - cpv[k] * un;
        uv[k] = un;
    }
    float4* o4 = reinterpret_cast<float4*>(out + (size_t)row * NN + base);
    #pragma unroll
    for (int k = 0; k < CH / 4; ++k) {
        o4[k] = make_float4(uv[4*k+0], uv[4*k+1], uv[4*k+2], uv[4*k+3]);
    }
}

extern "C" void kernel_launch(void* const* d_in, const int* in_sizes, int n_in,
                              void* d_out, int out_size, void* d_ws, size_t ws_size,
                              hipStream_t stream) {
    const float* alpha = (const float*)d_in[0];
    const float* fvec  = (const float*)d_in[1];
    float* out = (float*)d_out;
    const int nrows = out_size / NN;   // 2048
    thomas_scan_kernel<<<nrows, TB, 0, stream>>>(alpha, fvec, out);
}

// Round 2
// 129.730 us; speedup vs baseline: 1.0752x; 1.0752x over previous
//
#include <hip/hip_runtime.h>

// Batched Thomas solve, B=2048 rows, N=8192, fp32.
// One block per row; TB=512 threads x CH=16-element contiguous chunks.
// Forward recurrence (cp,dp) in homogeneous coords is linear; chunk maps
// [[p,0,q],[r,s,t],[u,0,v]] are closed under composition; normalize v==1.
// Scan structure: wave-level shuffle scan (no barriers) + single 8-entry
// cross-wave LDS exchange. 2 barriers total (was 18 in R1).
// CH=16 keeps va+vf+cpv+dpv = 64 regs -> no compiler re-loads inside the
// serial Phase-C recurrence (R1's VGPR=100 < 135 demand forced reloads).

#define NN 8192
#define TB 512
#define CH 16          // NN / TB
#define NWAVE (TB/64)  // 8

__device__ __forceinline__ float frcp(float x) { return __builtin_amdgcn_rcpf(x); }

__global__ __launch_bounds__(TB, 4)
void thomas_scan_kernel(const float* __restrict__ alpha,
                        const float* __restrict__ fvec,
                        float* __restrict__ out)
{
    __shared__ float wtot[NWAVE][6];  // forward wave-total maps (p,q,r,s,t,u; v==1)
    __shared__ float btot[NWAVE][2];  // backward wave-total affine (A,B)

    const int t    = threadIdx.x;
    const int lane = t & 63;
    const int wid  = t >> 6;
    const int row  = blockIdx.x;
    const float* __restrict__ arow = alpha + (size_t)row * NN;
    const int base = t * CH;

    // ---- load alpha chunk + halo, f chunk into registers ----
    float va[CH], vf[CH];
    {
        const float4* a4 = reinterpret_cast<const float4*>(arow + base);
        const float4* f4 = reinterpret_cast<const float4*>(fvec + base);
        #pragma unroll
        for (int k = 0; k < CH / 4; ++k) {
            float4 x = a4[k];
            va[4*k+0]=x.x; va[4*k+1]=x.y; va[4*k+2]=x.z; va[4*k+3]=x.w;
            float4 y = f4[k];
            vf[4*k+0]=y.x; vf[4*k+1]=y.y; vf[4*k+2]=y.z; vf[4*k+3]=y.w;
        }
    }
    const float aL = (t > 0)      ? arow[base - 1]  : 0.0f;  // => a_0 = 0
    const float aR = (t < TB - 1) ? arow[base + CH] : 0.0f;  // => c_{N-1} = 0

    // ---- Phase A: compose chunk map, then normalize so v == 1 ----
    float p=1.f, q=0.f, r=0.f, s=1.f, tt=0.f, u=0.f, v=1.f;
    #pragma unroll
    for (int k = 0; k < CH; ++k) {
        const float am1 = (k == 0)      ? aL : va[k-1];
        const float ap1 = (k == CH - 1) ? aR : va[k+1];
        const float ai = am1 * am1;
        const float bi = 1.0f + va[k]*va[k]*va[k];
        const float ci = ap1 * (ap1 + 2.0f);
        const float fi = vf[k];
        const float np = ci*u,        nq = ci*v;
        const float nr = fi*u - ai*r, ns = -ai*s, nt = fi*v - ai*tt;
        const float nu = bi*u - ai*p, nv = bi*v - ai*q;
        p=np; q=nq; r=nr; s=ns; tt=nt; u=nu; v=nv;
    }
    { const float inv = frcp(v); p*=inv; q*=inv; r*=inv; s*=inv; tt*=inv; u*=inv; }

    // ---- forward wave-inclusive shuffle scan (v==1 invariant) ----
    #pragma unroll
    for (int off = 1; off < 64; off <<= 1) {
        const float p1 = __shfl_up(p, off);
        const float q1 = __shfl_up(q, off);
        const float r1 = __shfl_up(r, off);
        const float s1 = __shfl_up(s, off);
        const float t1 = __shfl_up(tt, off);
        const float u1 = __shfl_up(u, off);
        if (lane >= off) {
            const float np = p*p1 + q*u1;
            const float nq = p*q1 + q;
            const float nr = r*p1 + s*r1 + tt*u1;
            const float ns = s*s1;
            const float nt = r*q1 + s*t1 + tt;
            const float nu = u*p1 + u1;
            const float nv = u*q1 + 1.0f;
            const float inv = frcp(nv);
            p=np*inv; q=nq*inv; r=nr*inv; s=ns*inv; tt=nt*inv; u=nu*inv;
        }
    }
    if (lane == 63) {
        wtot[wid][0]=p; wtot[wid][1]=q; wtot[wid][2]=r;
        wtot[wid][3]=s; wtot[wid][4]=tt; wtot[wid][5]=u;
    }
    __syncthreads();

    // exclusive-within-wave map
    float ep=__shfl_up(p,1), eq=__shfl_up(q,1), er=__shfl_up(r,1),
          es=__shfl_up(s,1), et=__shfl_up(tt,1), eu=__shfl_up(u,1);
    if (lane == 0) { ep=1.f; eq=0.f; er=0.f; es=1.f; et=0.f; eu=0.f; }

    // prefix over previous waves: P = T_{wid-1} o ... o T_0
    float Pp=1.f, Pq=0.f, Pr=0.f, Ps=1.f, Pt=0.f, Pu=0.f;
    for (int w = 0; w < wid; ++w) {
        const float p1=wtot[w][0], q1=wtot[w][1], r1=wtot[w][2],
                    s1=wtot[w][3], t1=wtot[w][4], u1=wtot[w][5];
        // P_new = T_w o P   (mine = T_w, earlier = P)
        const float np = p1*Pp + q1*Pu;
        const float nq = p1*Pq + q1;
        const float nr = r1*Pp + s1*Pr + t1*Pu;
        const float ns = s1*Ps;
        const float nt = r1*Pq + s1*Pt + t1;
        const float nu = u1*Pp + Pu;
        const float nv = u1*Pq + 1.0f;
        const float inv = frcp(nv);
        Pp=np*inv; Pq=nq*inv; Pr=nr*inv; Ps=ns*inv; Pt=nt*inv; Pu=nu*inv;
    }
    // E = ex o P ; incoming state = E applied to (0,0,1) -> (q,t,v), v==1
    float Eq, Et;
    {
        const float nq = ep*Pq + eq;
        const float nt = er*Pq + es*Pt + et;
        const float nv = eu*Pq + 1.0f;
        const float inv = frcp(nv);
        Eq = nq*inv; Et = nt*inv;
    }

    // ---- Phase C: true forward sweep, cp/dp in registers ----
    float cp = Eq, dp = Et;
    float cpv[CH], dpv[CH];
    #pragma unroll
    for (int k = 0; k < CH; ++k) {
        const float am1 = (k == 0)      ? aL : va[k-1];
        const float ap1 = (k == CH - 1) ? aR : va[k+1];
        const float ai = am1 * am1;
        const float bi = 1.0f + va[k]*va[k]*va[k];
        const float ci = ap1 * (ap1 + 2.0f);
        const float rd = frcp(bi - ai*cp);
        cp = ci * rd;
        dp = (vf[k] - ai*dp) * rd;
        cpv[k] = cp; dpv[k] = dp;
    }

    // ---- Phase D: backward affine chunk map u_left = A*u_right + B ----
    float A = 1.0f, Bb = 0.0f;
    #pragma unroll
    for (int k = CH - 1; k >= 0; --k) {
        Bb = dpv[k] - cpv[k]*Bb;
        A  = -cpv[k]*A;
    }
    // wave-inclusive suffix scan: comp(mine, later): A=A*A1, B=A*B1+B
    #pragma unroll
    for (int off = 1; off < 64; off <<= 1) {
        const float A1 = __shfl_down(A, off);
        const float B1 = __shfl_down(Bb, off);
        if (lane < 64 - off) { Bb = A*B1 + Bb; A = A*A1; }
    }
    if (lane == 0) { btot[wid][0] = A; btot[wid][1] = Bb; }
    __syncthreads();

    // exclusive-within-wave suffix
    float eA = __shfl_down(A, 1), eB = __shfl_down(Bb, 1);
    if (lane == 63) { eA = 1.0f; eB = 0.0f; }
    // suffix over later waves: S = T_{wid+1} o (T_{wid+2} o ( ... T_{NW-1}))
    float SA = 1.0f, SB = 0.0f;
    for (int w = NWAVE - 1; w > wid; --w) {
        const float A1 = btot[w][0], B1 = btot[w][1];
        SB = A1*SB + B1;   // comp(T_w, S): A'=A1*SA, B'=A1*SB+B1
        SA = A1*SA;
    }
    // incoming u for this thread: F = comp(ex, S) applied to 0 -> B_F
    const float u_in = eA*SB + eB;

    // ---- final back-substitution + float4 stores ----
    float uv[CH];
    float un = u_in;
    #pragma unroll
    for (int k = CH - 1; k >= 0; --k) {
        un = dpv[k] - cpv[k]*un;
        uv[k] = un;
    }
    float4* o4 = reinterpret_cast<float4*>(out + (size_t)row * NN + base);
    #pragma unroll
    for (int k = 0; k < CH / 4; ++k) {
        o4[k] = make_float4(uv[4*k+0], uv[4*k+1], uv[4*k+2], uv[4*k+3]);
    }
}

extern "C" void kernel_launch(void* const* d_in, const int* in_sizes, int n_in,
                              void* d_out, int out_size, void* d_ws, size_t ws_size,
                              hipStream_t stream) {
    const float* alpha = (const float*)d_in[0];
    const float* fvec  = (const float*)d_in[1];
    float* out = (float*)d_out;
    const int nrows = out_size / NN;   // 2048
    thomas_scan_kernel<<<nrows, TB, 0, stream>>>(alpha, fvec, out);
}